// Round 1
// baseline (120.997 us; speedup 1.0000x reference)
//
#include <hip/hip_runtime.h>
#include <hip/hip_bf16.h>

// ---------------------------------------------------------------------------
// LossNet: x (12288,128) fp32 -> scalar loss.
//   bsz=4096; xn = row-normalized x; xe/ye/ze = thirds.
//   7 exp-sim matrices (temp=0.1): only diag + row-sums consumed.
//   Tasks: 0 xx, 1 yy, 2 xy, 3 xz(ax), 4 yz(ay), 5 zx, 6 zy
// ---------------------------------------------------------------------------

typedef __attribute__((ext_vector_type(8))) short short8;   // 8 x bf16 (4 VGPRs)
typedef __attribute__((ext_vector_type(4))) float floatx4;  // MFMA acc

#define D      128   // feature dim
#define BM     128   // rows per block
#define BN     64    // cols per j-tile
#define JSPLIT 4     // column splits per (task, row-block)
#define NTASK  7
#define BPAD   136   // padded LDS row stride in shorts (+8 -> 2-way bank alias, free)

// ---------------------------------------------------------------------------
// Kernel 1: row-normalize fp32 -> bf16.  One wave (64 lanes) per row, 2 f32/lane.
// ---------------------------------------------------------------------------
__global__ __launch_bounds__(256) void normalize_kernel(
    const float* __restrict__ x, short* __restrict__ xn, int rows) {
  int row  = blockIdx.x * 4 + (threadIdx.x >> 6);
  int lane = threadIdx.x & 63;
  if (row >= rows) return;
  const float2* xr = (const float2*)(x + (size_t)row * D);
  float2 v = xr[lane];
  float s = v.x * v.x + v.y * v.y;
#pragma unroll
  for (int off = 1; off < 64; off <<= 1) s += __shfl_xor(s, off, 64);
  float scale = 1.0f / fmaxf(sqrtf(s), 1e-12f);
  __hip_bfloat162 h;
  h.x = __float2bfloat16(v.x * scale);
  h.y = __float2bfloat16(v.y * scale);
  ((__hip_bfloat162*)xn)[(size_t)row * 64 + lane] = h;
}

// ---------------------------------------------------------------------------
// Kernel 2: fused exp-sim.  Per block: BM rows of A (registers) x (bsz/JSPLIT)
// cols of B (LDS-staged 64x128 tiles).  MFMA 16x16x32 bf16, exp epilogue,
// row-sum partials in registers -> quad shuffle-reduce -> atomicAdd.
// Diag written directly (unique owner per element).
// ---------------------------------------------------------------------------
__global__ __launch_bounds__(256) void expsim_kernel(
    const short* __restrict__ xn,
    float* __restrict__ rowsum,   // [NTASK][bsz], pre-zeroed
    float* __restrict__ diag,     // [NTASK][bsz]
    int bsz) {
  const int aoff_t[NTASK] = {0, 1, 0, 0, 1, 2, 2};
  const int boff_t[NTASK] = {0, 1, 1, 2, 2, 0, 1};

  int nib   = bsz / BM;  // row-blocks per matrix
  int bx    = blockIdx.x;
  int task  = bx / (nib * JSPLIT);
  int rem   = bx % (nib * JSPLIT);
  int iblk  = rem / JSPLIT;
  int jpart = rem % JSPLIT;

  int arow0     = aoff_t[task] * bsz + iblk * BM;
  int brow_base = boff_t[task] * bsz;
  int jcols     = bsz / JSPLIT;
  int j0        = jpart * jcols;

  int tid  = threadIdx.x;
  int w    = tid >> 6;    // wave 0..3 -> rows w*32..w*32+31
  int lane = tid & 63;
  int quad = lane >> 4;   // C/D row group: row = quad*4 + reg
  int lm   = lane & 15;   // C/D col within tile; A/B m/n index

  // --- A fragments: held in registers for the whole block ---
  // A[m][k]: m = lm, k = quad*8 + j  (within a 16x32 slab, kk slabs along K)
  short8 afrag[2][4];
#pragma unroll
  for (int mi = 0; mi < 2; mi++) {
    int r = arow0 + w * 32 + mi * 16 + lm;
    const short8* ap = (const short8*)(xn + (size_t)r * D);
#pragma unroll
    for (int kk = 0; kk < 4; kk++) afrag[mi][kk] = ap[kk * 4 + quad];
  }

  __shared__ short ldsB[BN * BPAD];

  float rs[2][4];
#pragma unroll
  for (int mi = 0; mi < 2; mi++)
#pragma unroll
    for (int r = 0; r < 4; r++) rs[mi][r] = 0.0f;

  int rowg0 = iblk * BM + w * 32;

  for (int jt = 0; jt < jcols / BN; jt++) {
    int jbase = j0 + jt * BN;
    __syncthreads();
    // Stage B tile (64 rows x 128 k): 1024 16B-chunks over 256 threads.
#pragma unroll
    for (int it = 0; it < 4; it++) {
      int c  = it * 256 + tid;
      int br = c >> 4, c16 = c & 15;
      short8 v = *(const short8*)(xn + (size_t)(brow_base + jbase + br) * D + c16 * 8);
      *(short8*)(&ldsB[br * BPAD + c16 * 8]) = v;
    }
    __syncthreads();

    floatx4 acc[2][4];
#pragma unroll
    for (int mi = 0; mi < 2; mi++)
#pragma unroll
      for (int ni = 0; ni < 4; ni++) acc[mi][ni] = (floatx4){0.f, 0.f, 0.f, 0.f};

#pragma unroll
    for (int kk = 0; kk < 4; kk++) {
      short8 bfrag[4];
#pragma unroll
      for (int ni = 0; ni < 4; ni++)
        bfrag[ni] = *(const short8*)(&ldsB[(ni * 16 + lm) * BPAD + kk * 32 + quad * 8]);
#pragma unroll
      for (int mi = 0; mi < 2; mi++)
#pragma unroll
        for (int ni = 0; ni < 4; ni++)
          acc[mi][ni] = __builtin_amdgcn_mfma_f32_16x16x32_bf16(
              afrag[mi][kk], bfrag[ni], acc[mi][ni], 0, 0, 0);
    }

    // Epilogue: exp(10*c), row-sum partials, diag capture.
    // C/D layout: col = lm, row = quad*4 + reg  [m89-verified]
#pragma unroll
    for (int mi = 0; mi < 2; mi++) {
#pragma unroll
      for (int r = 0; r < 4; r++) {
        int rowg = rowg0 + mi * 16 + quad * 4 + r;
        float part = 0.0f;
#pragma unroll
        for (int ni = 0; ni < 4; ni++) {
          float e = __expf(10.0f * acc[mi][ni][r]);
          part += e;
          int colg = jbase + ni * 16 + lm;
          if (colg == rowg) diag[task * bsz + rowg] = e;
        }
        rs[mi][r] += part;
      }
    }
  }

  // Reduce row-sum partials across the 16 lanes of each quad, then one
  // atomicAdd per row per column-split.
#pragma unroll
  for (int mi = 0; mi < 2; mi++) {
#pragma unroll
    for (int r = 0; r < 4; r++) {
      float v = rs[mi][r];
      v += __shfl_xor(v, 1, 64);
      v += __shfl_xor(v, 2, 64);
      v += __shfl_xor(v, 4, 64);
      v += __shfl_xor(v, 8, 64);
      if (lm == 0) {
        int rowg = rowg0 + mi * 16 + quad * 4 + r;
        atomicAdd(&rowsum[task * bsz + rowg], v);
      }
    }
  }
}

// ---------------------------------------------------------------------------
// Kernel 3: final loss reduction (single block).
// ---------------------------------------------------------------------------
__global__ __launch_bounds__(256) void loss_kernel(
    const float* __restrict__ rowsum, const float* __restrict__ diag,
    float* __restrict__ out, int bsz) {
  int tid = threadIdx.x;
  float acc = 0.0f;
  for (int i = tid; i < bsz; i += 256) {
    float s_xx = rowsum[0 * bsz + i], d_xx = diag[0 * bsz + i];
    float s_yy = rowsum[1 * bsz + i], d_yy = diag[1 * bsz + i];
    float s_xy = rowsum[2 * bsz + i], d_xy = diag[2 * bsz + i];
    float s_ax = rowsum[3 * bsz + i], d_ax = diag[3 * bsz + i];
    float s_ay = rowsum[4 * bsz + i], d_ay = diag[4 * bsz + i];
    float s_zx = rowsum[5 * bsz + i], d_zx = diag[5 * bsz + i];
    float s_zy = rowsum[6 * bsz + i], d_zy = diag[6 * bsz + i];
    float denom = (s_xy - d_xy) + (s_xx - d_xx) + (s_yy - d_yy);
    float t = -2.0f * __logf(d_xy / denom);
    t -= __logf(d_ax / (s_ax - d_ax));
    t -= __logf(d_ay / (s_ay - d_ay));
    t -= __logf(d_zx / (s_zx - d_zx));
    t -= __logf(d_zy / (s_zy - d_zy));
    acc += t;
  }
  __shared__ float red[256];
  red[tid] = acc;
  __syncthreads();
  for (int s = 128; s > 0; s >>= 1) {
    if (tid < s) red[tid] += red[tid + s];
    __syncthreads();
  }
  if (tid == 0) out[0] = red[0] / (float)bsz;
}

// ---------------------------------------------------------------------------
extern "C" void kernel_launch(void* const* d_in, const int* in_sizes, int n_in,
                              void* d_out, int out_size, void* d_ws, size_t ws_size,
                              hipStream_t stream) {
  const float* x = (const float*)d_in[0];
  int rows = in_sizes[0] / D;   // 12288
  int bsz  = rows / 3;          // 4096

  char*  ws       = (char*)d_ws;
  short* xn       = (short*)ws;                        // rows*D bf16
  size_t xn_bytes = (size_t)rows * D * sizeof(short);  // 3 MiB
  float* rowsum   = (float*)(ws + xn_bytes);           // [7][bsz]
  float* dg       = rowsum + NTASK * bsz;              // [7][bsz]

  hipMemsetAsync(rowsum, 0, (size_t)NTASK * bsz * sizeof(float), stream);

  normalize_kernel<<<rows / 4, 256, 0, stream>>>(x, xn, rows);

  int nib = bsz / BM;  // 32
  expsim_kernel<<<NTASK * nib * JSPLIT, 256, 0, stream>>>(xn, rowsum, dg, bsz);

  loss_kernel<<<1, 256, 0, stream>>>(rowsum, dg, (float*)d_out, bsz);
}